// Round 1
// baseline (203.044 us; speedup 1.0000x reference)
//
#include <hip/hip_runtime.h>
#include <hip/hip_bf16.h>

#define NNODES   163842
#define INF      32
#define OUTF     64
#define NPOS     25
#define KTOT     800      // 25*32
#define MT       64       // nodes per block
#define NTHREADS 256

typedef float  f32x4  __attribute__((ext_vector_type(4)));
typedef __bf16 bf16x8 __attribute__((ext_vector_type(8)));
typedef __bf16 bf16x4 __attribute__((ext_vector_type(4)));

// ---------------- precompute: cast x and W to bf16 into workspace ----------------
__global__ void cvt_kernel(const float* __restrict__ x, const float* __restrict__ W,
                           __bf16* __restrict__ xb, __bf16* __restrict__ wb) {
    int tid = blockIdx.x * blockDim.x + threadIdx.x;
    int stride = gridDim.x * blockDim.x;
    const f32x4* x4 = (const f32x4*)x;
    bf16x4* xb4 = (bf16x4*)xb;
    const int nx4 = NNODES * INF / 4;          // 1,310,736
    for (int j = tid; j < nx4; j += stride) {
        f32x4 v = x4[j];
        bf16x4 o;
        #pragma unroll
        for (int k = 0; k < 4; ++k) o[k] = (__bf16)v[k];
        xb4[j] = o;
    }
    const f32x4* w4 = (const f32x4*)W;
    bf16x4* wb4 = (bf16x4*)wb;
    const int nw4 = OUTF * KTOT / 4;           // 12,800
    for (int j = tid; j < nw4; j += stride) {
        f32x4 v = w4[j];
        bf16x4 o;
        #pragma unroll
        for (int k = 0; k < 4; ++k) o[k] = (__bf16)v[k];
        wb4[j] = o;
    }
}

// ---------------- main fused gather + MFMA GEMM ----------------
__launch_bounds__(NTHREADS)
__global__ void conv_mfma(const int* __restrict__ nidx, const float* __restrict__ nwt,
                          const __bf16* __restrict__ xb, const __bf16* __restrict__ wb,
                          const float* __restrict__ bias, float* __restrict__ out) {
    __shared__ int   idxs[MT * 75];                  // 19200 B
    __shared__ float wts [MT * 75];                  // 19200 B
    __shared__ __align__(16) __bf16 feat[MT][48];    // 6144 B (32 ch + 16 pad)

    const int tid  = threadIdx.x;
    const int base = blockIdx.x * MT;

    // stage this block's indices + weights, fully coalesced
    {
        const long gbase = (long)base * 75;
        const long tot   = (long)NNODES * 75;
        for (int i = tid; i < MT * 75; i += NTHREADS) {
            long g = gbase + i;
            if (g < tot) { idxs[i] = nidx[g]; wts[i] = nwt[g]; }
            else         { idxs[i] = 0;       wts[i] = 0.0f;  }
        }
    }

    const int lane = tid & 63;
    const int wave = tid >> 6;       // 0..3 -> M rows 16*wave..16*wave+15
    // gather-phase mapping: 4 threads per node, 8 channels each
    const int gn = tid >> 2;         // 0..63
    const int gc = (tid & 3) * 8;    // 0,8,16,24
    // mfma-phase mapping
    const int arow = lane & 15;
    const int kgrp = lane >> 4;      // 0..3

    f32x4 acc[4] = {{0,0,0,0},{0,0,0,0},{0,0,0,0},{0,0,0,0}};

    __syncthreads();

    for (int p = 0; p < NPOS; ++p) {
        // ---- gather: feat[gn][gc..gc+7] = sum_v w_v * x[idx_v][gc..gc+7] ----
        {
            const int ib = gn * 75 + p * 3;
            const int i0 = idxs[ib+0], i1 = idxs[ib+1], i2 = idxs[ib+2];
            const float w0 = wts[ib+0], w1 = wts[ib+1], w2 = wts[ib+2];
            bf16x8 v0 = *(const bf16x8*)(xb + i0 * INF + gc);
            bf16x8 v1 = *(const bf16x8*)(xb + i1 * INF + gc);
            bf16x8 v2 = *(const bf16x8*)(xb + i2 * INF + gc);
            bf16x8 fv;
            #pragma unroll
            for (int j = 0; j < 8; ++j) {
                float f = w0 * (float)v0[j] + w1 * (float)v1[j] + w2 * (float)v2[j];
                fv[j] = (__bf16)f;
            }
            *(bf16x8*)(&feat[gn][gc]) = fv;
        }
        __syncthreads();
        // ---- mfma: acc += featchunk(64x32) @ Wchunk(32x64) ----
        {
            bf16x8 afrag = *(const bf16x8*)(&feat[16*wave + arow][8*kgrp]);
            const int koff = p * 32 + 8 * kgrp;
            #pragma unroll
            for (int nb = 0; nb < 4; ++nb) {
                bf16x8 bfrag = *(const bf16x8*)(wb + (16*nb + arow) * KTOT + koff);
                acc[nb] = __builtin_amdgcn_mfma_f32_16x16x32_bf16(afrag, bfrag, acc[nb], 0, 0, 0);
            }
        }
        __syncthreads();
    }

    // ---- epilogue: D layout col=lane&15, row=4*(lane>>4)+reg (m89-verified) ----
    #pragma unroll
    for (int nb = 0; nb < 4; ++nb) {
        const int col = 16*nb + arow;
        const float bv = bias[col];
        #pragma unroll
        for (int r = 0; r < 4; ++r) {
            const int row = base + 16*wave + 4*kgrp + r;
            if (row < NNODES) out[(long)row * OUTF + col] = acc[nb][r] + bv;
        }
    }
}

// ---------------- safety fallback (no workspace needed), fp32 ----------------
__global__ void conv_fallback(const float* __restrict__ x, const int* __restrict__ nidx,
                              const float* __restrict__ nwt, const float* __restrict__ W,
                              const float* __restrict__ bias, float* __restrict__ out) {
    __shared__ float feat[KTOT];
    const int n = blockIdx.x;
    const int t = threadIdx.x;   // 64
    for (int e = t; e < KTOT; e += 64) {
        const int p = e >> 5, c = e & 31;
        const int ib = n * 75 + p * 3;
        float a = 0.0f;
        #pragma unroll
        for (int v = 0; v < 3; ++v)
            a += nwt[ib+v] * x[nidx[ib+v] * INF + c];
        feat[e] = a;
    }
    __syncthreads();
    float a = bias[t];
    const float* wr = W + t * KTOT;
    for (int k = 0; k < KTOT; ++k) a += feat[k] * wr[k];
    out[(long)n * OUTF + t] = a;
}

extern "C" void kernel_launch(void* const* d_in, const int* in_sizes, int n_in,
                              void* d_out, int out_size, void* d_ws, size_t ws_size,
                              hipStream_t stream) {
    const float* x    = (const float*)d_in[0];
    const int*   nidx = (const int*)  d_in[1];
    const float* nwt  = (const float*)d_in[2];
    const float* W    = (const float*)d_in[3];
    const float* bias = (const float*)d_in[4];
    float* out = (float*)d_out;

    const size_t need = (size_t)NNODES * INF * 2 + (size_t)OUTF * KTOT * 2;
    if (ws_size < need) {
        conv_fallback<<<NNODES, 64, 0, stream>>>(x, nidx, nwt, W, bias, out);
        return;
    }

    __bf16* xb = (__bf16*)d_ws;
    __bf16* wb = xb + (size_t)NNODES * INF;

    cvt_kernel<<<1024, NTHREADS, 0, stream>>>(x, W, xb, wb);
    const int nblocks = (NNODES + MT - 1) / MT;   // 2561
    conv_mfma<<<nblocks, NTHREADS, 0, stream>>>(nidx, nwt, xb, wb, bias, out);
}